// Round 5
// baseline (1329.621 us; speedup 1.0000x reference)
//
#include <hip/hip_runtime.h>

#define TPB 256

typedef _Float16 f16;
typedef __attribute__((ext_vector_type(8))) _Float16 f16x8;
typedef __attribute__((ext_vector_type(16))) float f32x16;

#define GLD_LDS(g, l) __builtin_amdgcn_global_load_lds( \
    (const __attribute__((address_space(1))) void*)(g), \
    (__attribute__((address_space(3))) void*)(l), 16, 0, 0)

// ---------- weight pack: w[Cout][CinSrc][T] f32 -> Wp[t][kb64][coP][64] f16 ----------
__global__ __launch_bounds__(TPB)
void packw_k(const float* __restrict__ w, f16* __restrict__ dst,
             int Cout, int CinUse, int CinSrc, int T, int coP, int KB)
{
    __shared__ float tile[16 * 577];
    const int RL = 64 * T;
    const int kb = blockIdx.x;
    const int coT = blockIdx.y;
    const int tid = threadIdx.x;
    const int n = 16 * RL;
    for (int idx = tid; idx < n; idx += TPB) {
        const int row = idx / RL;
        const int j = idx - row * RL;
        const int co = coT * 16 + row;
        const int k = kb * 64 + j / T;
        float v = 0.f;
        if (co < Cout && k < CinUse)
            v = w[((long)co * CinSrc + kb * 64) * T + j];
        tile[row * 577 + j] = v;
    }
    __syncthreads();
    const int nst = 128 * T;
    for (int idx = tid; idx < nst; idx += TPB) {
        const int g = idx & 7;
        const int t = (idx >> 3) % T;
        const int co = idx / (8 * T);
        f16x8 hv;
#pragma unroll
        for (int e = 0; e < 8; ++e)
            hv[e] = (f16)tile[co * 577 + (g * 8 + e) * T + t];
        *(f16x8*)&dst[(((long)t * KB + kb) * coP + coT * 16 + co) * 64 + g * 8] = hv;
    }
}

// ---------- transpose-cvt: src[B][C][HW] -> dst[B][HW][ldk] f16 at colOff ----------
template <typename ST, int RELU>
__global__ __launch_bounds__(TPB)
void tc_k(const ST* __restrict__ src, f16* __restrict__ dst,
          int C, int HW, int ldk, int colOff)
{
    __shared__ float t32[32 * 33];
    const int pT = blockIdx.x, cT = blockIdx.y, bb = blockIdx.z;
    const int tid = threadIdx.x;
#pragma unroll
    for (int pass = 0; pass < 4; ++pass) {
        const int ch = tid / 32 + pass * 8;
        const int px = tid % 32;
        const int c = cT * 32 + ch, p = pT * 32 + px;
        float v = 0.f;
        if (c < C && p < HW) v = (float)src[((long)bb * C + c) * HW + p];
        if (RELU) v = fmaxf(v, 0.f);
        t32[ch * 33 + px] = v;
    }
    __syncthreads();
#pragma unroll
    for (int pass = 0; pass < 4; ++pass) {
        const int px = tid / 32 + pass * 8;
        const int ch = tid % 32;
        const int p = pT * 32 + px, c = cT * 32 + ch;
        if (p < HW && c < C)
            dst[((long)bb * HW + p) * ldk + colOff + c] = (f16)t32[ch * 33 + px];
    }
}

// ---------- MFMA implicit-GEMM conv: 2-phase double-buffered, BK=32 ----------
// X: [B][NP][Cinp] f16 pixel-major. Wp: [t][kb64][coP][64] f16.
// Block 128(co) x 256(px), 4 waves 2x2, wave tile 64x128, 16 MFMA/step.
// LDS per phase: A 8KB (paired-row swz) + B 16KB = 24KB; dbuf 48KB.
// OUTMODE: 0=f32, 1=f16, 2=atomicAdd f32, 3=f16 pixel-major (ldOut).
template <int OUTMODE, int ASPPZ, int RELUOUT>
__global__ __launch_bounds__(TPB, 2)
void mconv(const f16* __restrict__ X, const f16* __restrict__ Wp,
           const f16* __restrict__ guard, void* __restrict__ out_,
           int Cinp, int Cout, int H, int W, int ks, int dil,
           int uPerTap, int zLen, int uTot, long outBStride,
           int coP, int ldOut, int NM, int NB, int NZ)
{
    __shared__ char SH[49152];
    const int tid = threadIdx.x;

    // ---- XCD chunk-swizzle (m204 bijective) + decode (mt fastest, nt slowest) ----
    int wg;
    {
        const int orig = blockIdx.x, nwg = gridDim.x;
        const int q = nwg >> 3, r = nwg & 7;
        const int xcd = orig & 7, off = orig >> 3;
        wg = (xcd < r ? xcd * (q + 1) : r * (q + 1) + (xcd - r) * q) + off;
    }
    const int mt = wg % NM; wg /= NM;
    const int b  = wg % NB; wg /= NB;
    const int z  = wg % NZ;
    const int nt = wg / NZ;
    const int co0 = mt * 128;
    const int NP = H * W;

    int tap0, kb0, uB, uE, dl = dil, kss = ks;
    long woff = 0, ooff = 0;
    int p0, pMax = NP;
    if (ASPPZ) {
        int br;
        if (z == 0) { br = 0; tap0 = 0; kss = 1; dl = 1; }
        else { br = 1 + (z - 1) / 9; tap0 = (z - 1) % 9; kss = 3;
               dl = (br == 1) ? 6 : (br == 2 ? 12 : 18); }
        woff = (br == 0) ? 0L : (br == 1 ? 524288L : (br == 2 ? 5242880L : 9961472L));
        ooff = (long)br * 278784L;
        const int dy0 = (tap0 / kss - (kss >> 1)) * dl;
        const int yLo = max(0, -dy0), yHi = min(H, H - dy0);
        p0 = yLo * W + nt * 256;
        pMax = yHi * W;
        if (p0 >= pMax) return;
        uB = 0; uE = uPerTap; kb0 = 0;
    } else {
        p0 = nt * 256;
        uB = z * zLen; uE = min(uTot, uB + zLen);
        tap0 = uB / uPerTap; kb0 = uB - tap0 * uPerTap;
    }
    const int half = kss >> 1;

    // ---- per-lane staging geometry (paired-row swizzle) ----
    const int wid = tid >> 6, lane = tid & 63;
    const int srl_w = lane >> 3;                 // super-row within wave's 1KB
    const int slot  = lane & 7;
    const int ssw   = slot ^ srl_w;              // logical slot
    const int oddw  = ssw & 1;
    const int gw    = ssw >> 1;                  // k-granule [0,4)
    const int wofs  = wid * 1024;

    // A source offsets (2 rounds): co row within [0,128)
    int aofs[2];
#pragma unroll
    for (int r = 0; r < 2; ++r) {
        const int coRow = r * 64 + wid * 16 + srl_w * 2 + oddw;
        aofs[r] = coRow * 64 + gw * 8;
    }
    // B pixel rows (4 rounds)
    int rowB[4];
#pragma unroll
    for (int r = 0; r < 4; ++r)
        rowB[r] = r * 64 + wid * 16 + srl_w * 2 + oddw;

    const long coStr = (long)coP * 64;
    const int KB64 = uPerTap >> 1;

    // ---- stage cursor state ----
    int sTap = tap0, sKb = kb0;
    const f16* Wt;
    const f16* Pr[4];
    auto refresh = [&]() {
        const int ky = sTap / kss, kx = sTap - ky * kss;
        const int dy = (ky - half) * dl, dx = (kx - half) * dl;
#pragma unroll
        for (int r = 0; r < 4; ++r) {
            const int p = p0 + rowB[r];
            bool v = p < pMax;
            const int py = v ? p / W : 0;
            const int px = v ? p - py * W : 0;
            const int sy = py + dy, sx = px + dx;
            v = v && ((unsigned)sy < (unsigned)H) && ((unsigned)sx < (unsigned)W);
            Pr[r] = v ? (X + ((long)b * NP + (long)sy * W + sx) * Cinp + gw * 8)
                      : (guard + gw * 8);
        }
        Wt = Wp + woff + ((long)sTap * KB64 * coP + (long)co0) * 64;
    };
    auto stage = [&](char* bB) {
        const f16* wsrc = Wt + (long)(sKb >> 1) * coStr + ((sKb & 1) << 5);
        GLD_LDS(wsrc + aofs[0], bB + wofs);
        GLD_LDS(wsrc + aofs[1], bB + 4096 + wofs);
        const long kcol = (long)sKb << 5;
        GLD_LDS(Pr[0] + kcol, bB + 8192 + wofs);
        GLD_LDS(Pr[1] + kcol, bB + 12288 + wofs);
        GLD_LDS(Pr[2] + kcol, bB + 16384 + wofs);
        GLD_LDS(Pr[3] + kcol, bB + 20480 + wofs);
    };
    auto advance = [&]() {
        if (++sKb == uPerTap) { sKb = 0; ++sTap; refresh(); }
    };

    // ---- compute-role constants ----
    const int wm = wid >> 1, wn = wid & 1;
    const int r32 = lane & 31, hh = lane >> 5;
    const int srl_c = (r32 >> 1) & 7;
    const int odd_c = r32 & 1;
    const int aRow16 = (wm * 32 + (r32 >> 1)) * 8;        // slot base (A)
    const int bRow16 = (wn * 64 + (r32 >> 1)) * 8;        // slot base (B)

    f32x16 acc[2][4];
#pragma unroll
    for (int i = 0; i < 2; ++i)
#pragma unroll
        for (int j = 0; j < 4; ++j) acc[i][j] = (f32x16)(0.f);

    // ---- prologue ----
    refresh();
    stage(SH);
    if (uB + 1 < uE) advance();
    __syncthreads();

    // ---- 2-phase main loop: stage(next) || compute(cur), one barrier ----
    for (int u = uB; u < uE; ++u) {
        const int cur = (u - uB) & 1;
        if (u + 1 < uE) {
            stage(SH + (cur ^ 1) * 24576);
            if (u + 2 < uE) advance();
        }
        const char* bB = SH + cur * 24576;
#pragma unroll
        for (int kh = 0; kh < 2; ++kh) {
            const int g = kh * 2 + hh;
            const int sv = (g * 2 + odd_c) ^ srl_c;
            const int aoff = (aRow16 + sv) << 4;
            const int boff = 8192 + ((bRow16 + sv) << 4);
            const f16x8 a0 = *(const f16x8*)(bB + aoff);
            const f16x8 a1 = *(const f16x8*)(bB + aoff + 2048);
            const f16x8 b0 = *(const f16x8*)(bB + boff);
            const f16x8 b1 = *(const f16x8*)(bB + boff + 2048);
            const f16x8 b2 = *(const f16x8*)(bB + boff + 4096);
            const f16x8 b3 = *(const f16x8*)(bB + boff + 6144);
            acc[0][0] = __builtin_amdgcn_mfma_f32_32x32x16_f16(a0, b0, acc[0][0], 0, 0, 0);
            acc[0][1] = __builtin_amdgcn_mfma_f32_32x32x16_f16(a0, b1, acc[0][1], 0, 0, 0);
            acc[0][2] = __builtin_amdgcn_mfma_f32_32x32x16_f16(a0, b2, acc[0][2], 0, 0, 0);
            acc[0][3] = __builtin_amdgcn_mfma_f32_32x32x16_f16(a0, b3, acc[0][3], 0, 0, 0);
            acc[1][0] = __builtin_amdgcn_mfma_f32_32x32x16_f16(a1, b0, acc[1][0], 0, 0, 0);
            acc[1][1] = __builtin_amdgcn_mfma_f32_32x32x16_f16(a1, b1, acc[1][1], 0, 0, 0);
            acc[1][2] = __builtin_amdgcn_mfma_f32_32x32x16_f16(a1, b2, acc[1][2], 0, 0, 0);
            acc[1][3] = __builtin_amdgcn_mfma_f32_32x32x16_f16(a1, b3, acc[1][3], 0, 0, 0);
        }
        __syncthreads();
    }

    // ---- epilogue ----
    const long outB = (long)b * outBStride + ooff;
#pragma unroll
    for (int mi = 0; mi < 2; ++mi)
#pragma unroll
    for (int ni = 0; ni < 4; ++ni)
#pragma unroll
    for (int j = 0; j < 16; ++j) {
        const int m = wm * 64 + mi * 32 + 4 * hh + (j & 3) + 8 * (j >> 2);
        const int n = wn * 128 + ni * 32 + r32;
        const int co = co0 + m;
        const int p = p0 + n;
        if (co < Cout && p < pMax) {
            float v = acc[mi][ni][j];
            if (RELUOUT) v = fmaxf(v, 0.f);
            if (OUTMODE == 0)      ((float*)out_)[outB + (long)co * NP + p] = v;
            else if (OUTMODE == 1) ((f16*)out_)[outB + (long)co * NP + p] = (f16)v;
            else if (OUTMODE == 3) ((f16*)out_)[outB + (long)p * ldOut + co] = (f16)v;
            else atomicAdd(&((float*)out_)[outB + (long)co * NP + p], v);
        }
    }
}

// ---------- small helpers ----------
__global__ __launch_bounds__(TPB)
void wtrans_f32(const float* __restrict__ w, float* __restrict__ wT,
                int Cout, int Cin, int T)
{
    __shared__ float tile[32 * (32 * 9 + 1)];
    const int rowlen = 32 * T + 1;
    const int co0 = blockIdx.y * 32;
    const int ci0 = blockIdx.x * 32;
    const int n = 32 * 32 * T;
    const int tid = threadIdx.x;
    for (int l = tid; l < n; l += TPB) {
        int co = l / (32 * T);
        int rem = l - co * (32 * T);
        int ci = rem / T;
        float v = 0.f;
        if (co0 + co < Cout && ci0 + ci < Cin)
            v = w[(size_t)(co0 + co) * Cin * T + (size_t)ci0 * T + rem];
        tile[co * rowlen + rem] = v;
    }
    __syncthreads();
    for (int l = tid; l < n; l += TPB) {
        int co = l & 31;
        int ci = (l >> 5) & 31;
        int t = l >> 10;
        if (co0 + co < Cout && ci0 + ci < Cin)
            wT[((size_t)t * Cin + (ci0 + ci)) * Cout + (co0 + co)] = tile[co * rowlen + ci * T + t];
    }
}

__global__ __launch_bounds__(TPB)
void gpool_k(const float* __restrict__ in, float* __restrict__ gp, int HW, float inv)
{
    const int bc = blockIdx.x;
    const float* p = in + (size_t)bc * HW;
    float s = 0.f;
    for (int i = threadIdx.x; i < HW; i += TPB) s += p[i];
#pragma unroll
    for (int off = 32; off > 0; off >>= 1) s += __shfl_down(s, off, 64);
    __shared__ float red[4];
    if ((threadIdx.x & 63) == 0) red[threadIdx.x >> 6] = s;
    __syncthreads();
    if (threadIdx.x == 0) gp[bc] = (red[0] + red[1] + red[2] + red[3]) * inv;
}

__global__ __launch_bounds__(TPB)
void poolconv_k(const float* __restrict__ poolT, const float* __restrict__ gp,
                float* __restrict__ gpr)
{
    const int b = blockIdx.x, c = threadIdx.x;
    const float* g = gp + (size_t)b * 2048;
    float s = 0.f;
    for (int k = 0; k < 2048; ++k) s = fmaf(poolT[(size_t)k * 256 + c], g[k], s);
    gpr[b * 256 + c] = fmaxf(s, 0.f);
}

__global__ __launch_bounds__(TPB)
void gpc_k(const float* __restrict__ aprojT, const float* __restrict__ gpr,
           float* __restrict__ gpc)
{
    const int b = blockIdx.x, c = threadIdx.x;
    const float* g = gpr + (size_t)b * 256;
    const float* w = aprojT + (size_t)1024 * 256;
    float s = 0.f;
    for (int j = 0; j < 256; ++j) s = fmaf(w[(size_t)j * 256 + c], g[j], s);
    gpc[b * 256 + c] = s;
}

__global__ __launch_bounds__(TPB)
void biasfill_k(const float* __restrict__ gpc, float* __restrict__ yb)
{
    const int idx = blockIdx.x * TPB + threadIdx.x;
    if (idx >= 2 * 256 * 1089) return;
    const int c = (idx / 1089) & 255;
    const int b = idx / (256 * 1089);
    yb[idx] = gpc[b * 256 + c];
}

// ---------- upsample 33->129 from pixel-major YBX, writes CCX cols 48..303 ----------
__global__ __launch_bounds__(TPB)
void ups2_k(const f16* __restrict__ ybx, f16* __restrict__ ccx)
{
    const int idx = blockIdx.x * TPB + threadIdx.x;
    if (idx >= 2 * 16641 * 32) return;
    const int cg = idx & 31;
    const int p = (idx >> 5) % 16641;
    const int b = idx / (16641 * 32);
    const int oy = p / 129, ox = p % 129;
    const float sc = 33.0f / 129.0f;
    const float sx = (ox + 0.5f) * sc - 0.5f;
    const float sy = (oy + 0.5f) * sc - 0.5f;
    int ix0 = (int)floorf(sx), iy0 = (int)floorf(sy);
    const float fx = sx - ix0, fy = sy - iy0;
    int ix1 = min(32, max(0, ix0 + 1)); ix0 = min(32, max(0, ix0));
    int iy1 = min(32, max(0, iy0 + 1)); iy0 = min(32, max(0, iy0));
    const f16* base = ybx + (long)b * 1089 * 256 + cg * 8;
    const f16x8 v00 = *(const f16x8*)(base + ((long)iy0 * 33 + ix0) * 256);
    const f16x8 v01 = *(const f16x8*)(base + ((long)iy0 * 33 + ix1) * 256);
    const f16x8 v10 = *(const f16x8*)(base + ((long)iy1 * 33 + ix0) * 256);
    const f16x8 v11 = *(const f16x8*)(base + ((long)iy1 * 33 + ix1) * 256);
    f16x8 r;
#pragma unroll
    for (int e = 0; e < 8; ++e) {
        const float a0 = (float)v00[e] + ((float)v01[e] - (float)v00[e]) * fx;
        const float a1 = (float)v10[e] + ((float)v11[e] - (float)v10[e]) * fx;
        r[e] = (f16)(a0 + (a1 - a0) * fy);
    }
    *(f16x8*)(ccx + ((long)b * 16641 + p) * 320 + 48 + cg * 8) = r;
}

// ---------- cw2 1x1 conv (relu on input) ----------
template <int NC>
__global__ __launch_bounds__(TPB)
void conv1x1_small(const float* __restrict__ in, const float* __restrict__ wT,
                   const float* __restrict__ bias, float* __restrict__ out, int HW)
{
    __shared__ float wsm[256 * NC];
    const int tid = threadIdx.x;
    for (int l = tid; l < 256 * NC; l += TPB) wsm[l] = wT[l];
    __syncthreads();
    const int b = blockIdx.y;
    const int p = blockIdx.x * TPB + tid;
    if (p >= HW) return;
    const float* inB = in + (size_t)b * 256 * HW + p;
    float acc[NC];
#pragma unroll
    for (int c = 0; c < NC; ++c) acc[c] = 0.f;
    for (int k = 0; k < 256; ++k) {
        const float x = fmaxf(inB[(size_t)k * HW], 0.f);
#pragma unroll
        for (int c = 0; c < NC; ++c) acc[c] = fmaf(wsm[k * NC + c], x, acc[c]);
    }
    float* oB = out + (size_t)b * NC * HW + p;
#pragma unroll
    for (int c = 0; c < NC; ++c) oB[(size_t)c * HW] = acc[c] + bias[c];
}

// ---------- final: 129->513 bilinear + logits + NHWC features ----------
template <int NC>
__global__ __launch_bounds__(TPB)
void final_k(const float* __restrict__ x, float* __restrict__ logits,
             float* __restrict__ feats)
{
    const int idx = blockIdx.x * TPB + threadIdx.x;
    const long HW = 513L * 513L;
    if (idx >= 2 * 513 * 513) return;
    const int ox = idx % 513;
    int r = idx / 513;
    const int oy = r % 513;
    const int b = r / 513;
    const float sc = 129.0f / 513.0f;
    const float sx = (ox + 0.5f) * sc - 0.5f;
    const float sy = (oy + 0.5f) * sc - 0.5f;
    int ix0 = (int)floorf(sx), iy0 = (int)floorf(sy);
    const float fx = sx - ix0, fy = sy - iy0;
    int ix1 = min(128, max(0, ix0 + 1)); ix0 = min(128, max(0, ix0));
    int iy1 = min(128, max(0, iy0 + 1)); iy0 = min(128, max(0, iy0));
    const float* xb = x + (size_t)b * NC * 16641;
    const int i00 = iy0 * 129 + ix0, i01 = iy0 * 129 + ix1;
    const int i10 = iy1 * 129 + ix0, i11 = iy1 * 129 + ix1;
    float v[NC];
    float ss = 0.f;
#pragma unroll
    for (int c = 0; c < NC; ++c) {
        const float* s = xb + (size_t)c * 16641;
        const float a0 = s[i00] + (s[i01] - s[i00]) * fx;
        const float a1 = s[i10] + (s[i11] - s[i10]) * fx;
        const float vv = a0 + (a1 - a0) * fy;
        v[c] = vv;
        ss = fmaf(vv, vv, ss);
    }
    const long pix = (long)oy * 513 + ox;
#pragma unroll
    for (int c = 0; c < NC; ++c)
        logits[((size_t)b * NC + c) * HW + pix] = fmaf(6.f, v[c], -ss - 9.f);
    float* f = feats + ((size_t)b * HW + pix) * NC;
#pragma unroll
    for (int c = 0; c < NC; ++c) f[c] = v[c];
}

__global__ void centers_k(float* __restrict__ c0, float* __restrict__ c1)
{
    const int t = blockIdx.x * 64 + threadIdx.x;
    if (t < 256) c0[t] = (t / 16 == t % 16) ? 3.f : 0.f;
    const int u = t - 256;
    if (u >= 0 && u < 289) c1[u] = (u / 17 == u % 17) ? 3.f : 0.f;
}

// ---------------- host ----------------
extern "C" void kernel_launch(void* const* d_in, const int* in_sizes, int n_in,
                              void* d_out, int out_size, void* d_ws, size_t ws_size,
                              hipStream_t stream)
{
    const float* low_level = (const float*)d_in[0];
    const float* aspp_in   = (const float*)d_in[1];
    float* ws = (float*)d_ws;
    float* o  = (float*)d_out;

    // ---- ws layout (floats) ----
    f16*   GUARD   = (f16*)(ws + 0);                  //  4,096 fl (zeros)
    float* AR      = ws + 4096;                       //  8,520,192 fl: Apack, later C1O (alias)
    f16*   Apack   = (f16*)AR;
    float* C1O     = AR;
    f16*   AprojP  = (f16*)(ws + 8524288);            //  131,072 fl
    f16*   Cw1P    = (f16*)(ws + 8655360);            //  368,640 fl
    f16*   LlP     = (f16*)(ws + 9024000);            //  16,384 fl
    f16*   Xa      = (f16*)(ws + 9040384);            //  2,230,272 fl
    float* BRacc   = ws + 11270656;                   //  2,230,272 fl
    f16*   BRX     = (f16*)(ws + 13500928);           //  1,115,136 fl
    float* YB      = ws + 14616064;                   //    557,568 fl
    f16*   YBX     = (f16*)(ws + 15173632);           //    278,784 fl
    f16*   CCX     = (f16*)(ws + 16251184);           //  5,325,120 fl
    f16*   Xll     = (f16*)(ws + 21576304);           //  4,260,096 fl
    float* XB      = ws + 25836400;                   //    565,794 fl
    float* POOLT32 = ws + 26402194;                   //    524,288 fl
    float* APROJT32= ws + 26926482;                   //    327,680 fl
    float* CW2T    = ws + 27254162;                   //      4,608 fl
    float* GP      = ws + 27258770;                   //      4,096 fl
    float* GPR     = ws + 27262866;                   //        512 fl
    float* GPC     = ws + 27263378;                   //        512 fl

    const long L0o = 0, L1o = 8421408, C0o = 17369154, C1oo = 17369410,
               F0o = 17369699, F1o = 25791107;

    hipMemsetAsync(GUARD, 0, 4096 * sizeof(float), stream);
    hipMemsetAsync(CCX, 0, 10650240 * sizeof(f16), stream);  // once: pad cols stay 0

    // head-independent packs
    tc_k<float, 0><<<dim3(35, 64, 2), TPB, 0, stream>>>(aspp_in, Xa, 2048, 1089, 2048, 0);
    tc_k<float, 0><<<dim3(521, 8, 2), TPB, 0, stream>>>(low_level, Xll, 256, 16641, 256, 0);
    gpool_k<<<4096, TPB, 0, stream>>>(aspp_in, GP, 1089, 1.0f / 1089.0f);

    for (int h = 0; h < 2; ++h) {
        const float* pw    = (const float*)d_in[2 + h * 10 + 0];
        const float* w0    = (const float*)d_in[2 + h * 10 + 1];
        const float* w1    = (const float*)d_in[2 + h * 10 + 2];
        const float* w2    = (const float*)d_in[2 + h * 10 + 3];
        const float* w3    = (const float*)d_in[2 + h * 10 + 4];
        const float* poolw = (const float*)d_in[2 + h * 10 + 5];
        const float* aproj = (const float*)d_in[2 + h * 10 + 6];
        const float* cw1   = (const float*)d_in[2 + h * 10 + 7];
        const float* cw2   = (const float*)d_in[2 + h * 10 + 8];
        const float* cb2   = (const float*)d_in[2 + h * 10 + 9];

        // pooled branch -> per-(b,c) bias prefilled into YB
        wtrans_f32<<<dim3(64, 8), TPB, 0, stream>>>(poolw, POOLT32, 256, 2048, 1);
        wtrans_f32<<<dim3(40, 8), TPB, 0, stream>>>(aproj, APROJT32, 256, 1280, 1);
        poolconv_k<<<2, TPB, 0, stream>>>(POOLT32, GP, GPR);
        gpc_k<<<2, TPB, 0, stream>>>(APROJT32, GPR, GPC);
        biasfill_k<<<2178, TPB, 0, stream>>>(GPC, YB);

        // weight packs
        packw_k<<<dim3(32, 16), TPB, 0, stream>>>(w0, Apack,           256, 2048, 2048, 1, 256, 32);
        packw_k<<<dim3(32, 16), TPB, 0, stream>>>(w1, Apack + 524288,  256, 2048, 2048, 9, 256, 32);
        packw_k<<<dim3(32, 16), TPB, 0, stream>>>(w2, Apack + 5242880, 256, 2048, 2048, 9, 256, 32);
        packw_k<<<dim3(32, 16), TPB, 0, stream>>>(w3, Apack + 9961472, 256, 2048, 2048, 9, 256, 32);
        packw_k<<<dim3(16, 16), TPB, 0, stream>>>(aproj, AprojP, 256, 1024, 1280, 1, 256, 16);
        packw_k<<<dim3(5, 16),  TPB, 0, stream>>>(cw1, Cw1P, 256, 304, 304, 9, 256, 5);
        packw_k<<<dim3(4, 8),   TPB, 0, stream>>>(pw, LlP, 48, 256, 256, 1, 128, 4);

        // fused ASPP: NT=5, NZ=28, NB=2, NM=2 -> 560 blocks, atomic into zeroed BRacc
        hipMemsetAsync(BRacc, 0, 2230272 * sizeof(float), stream);
        mconv<2, 1, 0><<<560, TPB, 0, stream>>>(
            Xa, Apack, GUARD, BRacc, 2048, 256, 33, 33, 3, 1,
            64, 64, 64, 1024L * 1089, 256, 0, 2, 2, 28);
        // relu + transpose -> BRX, then aproj split-K: NT=5,NZ=4,NB=2,NM=2 -> 80 blocks
        tc_k<float, 1><<<dim3(35, 32, 2), TPB, 0, stream>>>(BRacc, BRX, 1024, 1089, 1024, 0);
        mconv<2, 0, 0><<<80, TPB, 0, stream>>>(
            BRX, AprojP, GUARD, YB, 1024, 256, 33, 33, 1, 1,
            32, 8, 32, 256L * 1089, 256, 0, 2, 2, 4);
        // relu + transpose YB -> YBX
        tc_k<float, 1><<<dim3(35, 8, 2), TPB, 0, stream>>>(YB, YBX, 256, 1089, 256, 0);
        // low-level 1x1 (48ch, relu) -> CCX cols 0..47: NT=66,NZ=1,NB=2,NM=1 -> 132
        mconv<3, 0, 1><<<132, TPB, 0, stream>>>(
            Xll, LlP, GUARD, CCX, 256, 48, 129, 129, 1, 1,
            8, 8, 8, 16641L * 320, 128, 320, 1, 2, 1);
        // upsample 33->129 -> CCX cols 48..303
        ups2_k<<<4161, TPB, 0, stream>>>(YBX, CCX);
        // cw1 3x3 tap-accumulating: NT=66,NZ=3,NB=2,NM=2 -> 792 blocks
        hipMemsetAsync(C1O, 0, 8520192 * sizeof(float), stream);
        mconv<2, 0, 0><<<792, TPB, 0, stream>>>(
            CCX, Cw1P, GUARD, C1O, 320, 256, 129, 129, 3, 1,
            10, 30, 90, 256L * 16641, 256, 0, 2, 2, 3);

        if (h == 0) {
            wtrans_f32<<<dim3(8, 1), TPB, 0, stream>>>(cw2, CW2T, 16, 256, 1);
            conv1x1_small<16><<<dim3(66, 2), TPB, 0, stream>>>(C1O, CW2T, cb2, XB, 16641);
            final_k<16><<<2057, TPB, 0, stream>>>(XB, o + L0o, o + F0o);
        } else {
            wtrans_f32<<<dim3(8, 1), TPB, 0, stream>>>(cw2, CW2T, 17, 256, 1);
            conv1x1_small<17><<<dim3(66, 2), TPB, 0, stream>>>(C1O, CW2T, cb2, XB, 16641);
            final_k<17><<<2057, TPB, 0, stream>>>(XB, o + L1o, o + F1o);
        }
    }
    centers_k<<<9, 64, 0, stream>>>(o + C0o, o + C1oo);
}

// Round 6
// 920.769 us; speedup vs baseline: 1.4440x; 1.4440x over previous
//
#include <hip/hip_runtime.h>

#define TPB 256

typedef _Float16 f16;
typedef __attribute__((ext_vector_type(8))) _Float16 f16x8;
typedef __attribute__((ext_vector_type(16))) float f32x16;

#define GLD_LDS(g, l) __builtin_amdgcn_global_load_lds( \
    (const __attribute__((address_space(1))) void*)(g), \
    (__attribute__((address_space(3))) void*)(l), 16, 0, 0)

// ---------- weight pack: w[Cout][CinSrc][T] f32 -> Wp[t][kb64][coP][64] f16 ----------
__global__ __launch_bounds__(TPB)
void packw_k(const float* __restrict__ w, f16* __restrict__ dst,
             int Cout, int CinUse, int CinSrc, int T, int coP, int KB)
{
    __shared__ float tile[16 * 577];
    const int RL = 64 * T;
    const int kb = blockIdx.x;
    const int coT = blockIdx.y;
    const int tid = threadIdx.x;
    const int n = 16 * RL;
    for (int idx = tid; idx < n; idx += TPB) {
        const int row = idx / RL;
        const int j = idx - row * RL;
        const int co = coT * 16 + row;
        const int k = kb * 64 + j / T;
        float v = 0.f;
        if (co < Cout && k < CinUse)
            v = w[((long)co * CinSrc + kb * 64) * T + j];
        tile[row * 577 + j] = v;
    }
    __syncthreads();
    const int nst = 128 * T;
    for (int idx = tid; idx < nst; idx += TPB) {
        const int g = idx & 7;
        const int t = (idx >> 3) % T;
        const int co = idx / (8 * T);
        f16x8 hv;
#pragma unroll
        for (int e = 0; e < 8; ++e)
            hv[e] = (f16)tile[co * 577 + (g * 8 + e) * T + t];
        *(f16x8*)&dst[(((long)t * KB + kb) * coP + coT * 16 + co) * 64 + g * 8] = hv;
    }
}

// ---------- transpose-cvt: src[S][C][HW] f32 -> dst[S][HW][ldk] f16 ----------
template <int RELU>
__global__ __launch_bounds__(TPB)
void tc_k(const float* __restrict__ src, f16* __restrict__ dst,
          int C, int HW, int ldk, int colOff)
{
    __shared__ float t32[32 * 33];
    const int pT = blockIdx.x, cT = blockIdx.y, bb = blockIdx.z;
    const int tid = threadIdx.x;
#pragma unroll
    for (int pass = 0; pass < 4; ++pass) {
        const int ch = tid / 32 + pass * 8;
        const int px = tid % 32;
        const int c = cT * 32 + ch, p = pT * 32 + px;
        float v = 0.f;
        if (c < C && p < HW) v = src[((long)bb * C + c) * HW + p];
        if (RELU) v = fmaxf(v, 0.f);
        t32[ch * 33 + px] = v;
    }
    __syncthreads();
#pragma unroll
    for (int pass = 0; pass < 4; ++pass) {
        const int px = tid / 32 + pass * 8;
        const int ch = tid % 32;
        const int p = pT * 32 + px, c = cT * 32 + ch;
        if (p < HW && c < C)
            dst[((long)bb * HW + p) * ldk + colOff + c] = (f16)t32[ch * 33 + px];
    }
}

// ---------- MFMA implicit-GEMM conv: 2-phase dbuf, BK=32, head-merged ----------
// X: [b][NP][Cinp] (+ head stride) f16 pixel-major. Wp: [t][kb64][coP][64] f16 (+ head stride).
// Block 128(co) x 256(px), 4 waves 2x2, wave tile 64x128, reg accumulation over taps.
// OUTMODE: 0=f32, 1=f16 ch-major, 2=atomicAdd f32, 3=f16 pixel-major (ldOut).
// ZMAP: 0 = plain (all taps, full K), 1 = ASPP table (z->branch/row-group), 2 = split-K (z over kb).
template <int OUTMODE, int ZMAP, int RELUOUT>
__global__ __launch_bounds__(TPB, 2)
void mconv(const f16* __restrict__ X, const f16* __restrict__ Wp,
           const f16* __restrict__ guard, void* __restrict__ out_,
           int Cinp, int Cout, int H, int W, int kss_, int dl_,
           int kbPerTap, int tapCnt_, int zKb,
           long xHstr, long wHstr, long oHstr, long outBStride,
           int coP, int ldOut, int NM, int NBH, int NZ)
{
    __shared__ char SH[49152];
    const int tid = threadIdx.x;

    int wg;
    {
        const int orig = blockIdx.x, nwg = gridDim.x;
        const int q = nwg >> 3, r = nwg & 7;
        const int xcd = orig & 7, off = orig >> 3;
        wg = (xcd < r ? xcd * (q + 1) : r * (q + 1) + (xcd - r) * q) + off;
    }
    const int mt = wg % NM; wg /= NM;
    const int bh = wg % NBH; wg /= NBH;
    const int z  = wg % NZ;
    const int nt = wg / NZ;
    const int b = bh & 1, hd = bh >> 1;
    const int co0 = mt * 128;
    const int NP = H * W;
    const long xBstr = (long)NP * Cinp;

    int kss = kss_, dl = dl_, tapStart = 0, tapCnt = tapCnt_, kbB = 0, kbE = kbPerTap;
    long woff = (long)hd * wHstr, ooff = (long)hd * oHstr;
    int p0 = nt * 256, pMax = NP;
    if (ZMAP == 1) {
        int br, grp;
        if (z == 0) { br = 0; grp = 1; kss = 1; dl = 1; tapStart = 0; tapCnt = 1; }
        else { br = 1 + (z - 1) / 3; grp = (z - 1) % 3;
               kss = 3; dl = (br == 1) ? 6 : (br == 2 ? 12 : 18);
               tapStart = grp * 3; tapCnt = 3; }
        woff += (br == 0) ? 0L : (br == 1 ? 524288L : (br == 2 ? 5242880L : 9961472L));
        ooff += (long)br * 278784L;
        const int dy0 = (kss == 1) ? 0 : (grp - 1) * dl;
        const int yLo = max(0, -dy0), yHi = min(H, H - dy0);
        p0 = yLo * W + nt * 256;
        pMax = yHi * W;
        if (p0 >= pMax) return;
    } else if (ZMAP == 2) {
        kbB = z * zKb; kbE = min(kbPerTap, kbB + zKb);
    }
    const int half = kss >> 1;
    const int y0t = p0 / W, y1t = min(p0 + 255, pMax - 1) / W;

    // valid tap list (block-uniform skip)
    int taps[9]; int nval = 0;
    for (int t = 0; t < tapCnt; ++t) {
        const int tp = tapStart + t;
        const int ky = tp / kss;
        const int dy = (ky - half) * dl;
        if (ZMAP == 1 || (y1t + dy >= 0 && y0t + dy < H)) taps[nval++] = tp;
    }
    const int kbN = kbE - kbB;
    const int nSteps = nval * kbN;
    if (nSteps == 0) return;

    // ---- staging geometry (paired-row swizzle) ----
    const int wid = tid >> 6, lane = tid & 63;
    const int srl_w = lane >> 3;
    const int slot  = lane & 7;
    const int ssw   = slot ^ srl_w;
    const int oddw  = ssw & 1;
    const int gw    = ssw >> 1;
    const int wofs  = wid * 1024;

    int aofs[2];
#pragma unroll
    for (int r = 0; r < 2; ++r) {
        const int coRow = r * 64 + wid * 16 + srl_w * 2 + oddw;
        aofs[r] = coRow * 64 + gw * 8;
    }
    int rowB[4];
#pragma unroll
    for (int r = 0; r < 4; ++r)
        rowB[r] = r * 64 + wid * 16 + srl_w * 2 + oddw;

    const long coStr = (long)coP * 64;
    const int KB64 = kbPerTap >> 1;

    // ---- stage cursor ----
    int vi = 0, sKb = kbB;
    const f16* Wt;
    const f16* Pr[4];
    auto refresh = [&]() {
        const int tp = taps[vi];
        const int ky = tp / kss, kx = tp - ky * kss;
        const int dy = (ky - half) * dl, dx = (kx - half) * dl;
#pragma unroll
        for (int r = 0; r < 4; ++r) {
            const int p = p0 + rowB[r];
            bool v = p < pMax;
            const int py = v ? p / W : 0;
            const int px = v ? p - py * W : 0;
            const int sy = py + dy, sx = px + dx;
            v = v && ((unsigned)sy < (unsigned)H) && ((unsigned)sx < (unsigned)W);
            Pr[r] = v ? (X + (long)b * xBstr + (long)hd * xHstr
                           + ((long)sy * W + sx) * (long)Cinp + gw * 8)
                      : (guard + gw * 8);
        }
        Wt = Wp + woff + ((long)tp * KB64 * coP + (long)co0) * 64;
    };
    auto stage = [&](char* bB) {
        const f16* wsrc = Wt + (long)(sKb >> 1) * coStr + ((sKb & 1) << 5);
        GLD_LDS(wsrc + aofs[0], bB + wofs);
        GLD_LDS(wsrc + aofs[1], bB + 4096 + wofs);
        const long kcol = (long)sKb << 5;
        GLD_LDS(Pr[0] + kcol, bB + 8192 + wofs);
        GLD_LDS(Pr[1] + kcol, bB + 12288 + wofs);
        GLD_LDS(Pr[2] + kcol, bB + 16384 + wofs);
        GLD_LDS(Pr[3] + kcol, bB + 20480 + wofs);
    };
    auto advance = [&]() {
        if (++sKb == kbE) { sKb = kbB; ++vi; refresh(); }
    };

    // ---- compute roles ----
    const int wm = wid >> 1, wn = wid & 1;
    const int r32 = lane & 31, hh = lane >> 5;
    const int srl_c = (r32 >> 1) & 7;
    const int odd_c = r32 & 1;
    const int aRow16 = (wm * 32 + (r32 >> 1)) * 8;
    const int bRow16 = (wn * 64 + (r32 >> 1)) * 8;

    f32x16 acc[2][4];
#pragma unroll
    for (int i = 0; i < 2; ++i)
#pragma unroll
        for (int j = 0; j < 4; ++j) acc[i][j] = (f32x16)(0.f);

    // ---- prologue ----
    refresh();
    stage(SH);
    if (nSteps > 1) advance();
    __syncthreads();

    // ---- 2-phase main loop ----
    for (int s = 0; s < nSteps; ++s) {
        const int cur = s & 1;
        if (s + 1 < nSteps) {
            stage(SH + (cur ^ 1) * 24576);
            if (s + 2 < nSteps) advance();
        }
        const char* bB = SH + cur * 24576;
#pragma unroll
        for (int kh = 0; kh < 2; ++kh) {
            const int g = kh * 2 + hh;
            const int sv = (g * 2 + odd_c) ^ srl_c;
            const int aoff = (aRow16 + sv) << 4;
            const int boff = 8192 + ((bRow16 + sv) << 4);
            const f16x8 a0 = *(const f16x8*)(bB + aoff);
            const f16x8 a1 = *(const f16x8*)(bB + aoff + 2048);
            const f16x8 b0 = *(const f16x8*)(bB + boff);
            const f16x8 b1 = *(const f16x8*)(bB + boff + 2048);
            const f16x8 b2 = *(const f16x8*)(bB + boff + 4096);
            const f16x8 b3 = *(const f16x8*)(bB + boff + 6144);
            acc[0][0] = __builtin_amdgcn_mfma_f32_32x32x16_f16(a0, b0, acc[0][0], 0, 0, 0);
            acc[0][1] = __builtin_amdgcn_mfma_f32_32x32x16_f16(a0, b1, acc[0][1], 0, 0, 0);
            acc[0][2] = __builtin_amdgcn_mfma_f32_32x32x16_f16(a0, b2, acc[0][2], 0, 0, 0);
            acc[0][3] = __builtin_amdgcn_mfma_f32_32x32x16_f16(a0, b3, acc[0][3], 0, 0, 0);
            acc[1][0] = __builtin_amdgcn_mfma_f32_32x32x16_f16(a1, b0, acc[1][0], 0, 0, 0);
            acc[1][1] = __builtin_amdgcn_mfma_f32_32x32x16_f16(a1, b1, acc[1][1], 0, 0, 0);
            acc[1][2] = __builtin_amdgcn_mfma_f32_32x32x16_f16(a1, b2, acc[1][2], 0, 0, 0);
            acc[1][3] = __builtin_amdgcn_mfma_f32_32x32x16_f16(a1, b3, acc[1][3], 0, 0, 0);
        }
        __syncthreads();
    }

    // ---- epilogue ----
    const long outB = (long)b * outBStride + ooff;
#pragma unroll
    for (int mi = 0; mi < 2; ++mi)
#pragma unroll
    for (int ni = 0; ni < 4; ++ni)
#pragma unroll
    for (int j = 0; j < 16; ++j) {
        const int m = wm * 64 + mi * 32 + 4 * hh + (j & 3) + 8 * (j >> 2);
        const int n = wn * 128 + ni * 32 + r32;
        const int co = co0 + m;
        const int p = p0 + n;
        if (co < Cout && p < pMax) {
            float v = acc[mi][ni][j];
            if (RELUOUT) v = fmaxf(v, 0.f);
            if (OUTMODE == 0)      ((float*)out_)[outB + (long)co * NP + p] = v;
            else if (OUTMODE == 1) ((f16*)out_)[outB + (long)co * NP + p] = (f16)v;
            else if (OUTMODE == 3) ((f16*)out_)[outB + (long)p * ldOut + co] = (f16)v;
            else atomicAdd(&((float*)out_)[outB + (long)co * NP + p], v);
        }
    }
}

// ---------- small helpers ----------
__global__ __launch_bounds__(TPB)
void wtrans_f32(const float* __restrict__ w, float* __restrict__ wT,
                int Cout, int Cin, int T)
{
    __shared__ float tile[32 * (32 * 9 + 1)];
    const int rowlen = 32 * T + 1;
    const int co0 = blockIdx.y * 32;
    const int ci0 = blockIdx.x * 32;
    const int n = 32 * 32 * T;
    const int tid = threadIdx.x;
    for (int l = tid; l < n; l += TPB) {
        int co = l / (32 * T);
        int rem = l - co * (32 * T);
        int ci = rem / T;
        float v = 0.f;
        if (co0 + co < Cout && ci0 + ci < Cin)
            v = w[(size_t)(co0 + co) * Cin * T + (size_t)ci0 * T + rem];
        tile[co * rowlen + rem] = v;
    }
    __syncthreads();
    for (int l = tid; l < n; l += TPB) {
        int co = l & 31;
        int ci = (l >> 5) & 31;
        int t = l >> 10;
        if (co0 + co < Cout && ci0 + ci < Cin)
            wT[((size_t)t * Cin + (ci0 + ci)) * Cout + (co0 + co)] = tile[co * rowlen + ci * T + t];
    }
}

__global__ __launch_bounds__(TPB)
void gpool_k(const float* __restrict__ in, float* __restrict__ gp, int HW, float inv)
{
    const int bc = blockIdx.x;
    const float* p = in + (size_t)bc * HW;
    float s = 0.f;
    for (int i = threadIdx.x; i < HW; i += TPB) s += p[i];
#pragma unroll
    for (int off = 32; off > 0; off >>= 1) s += __shfl_down(s, off, 64);
    __shared__ float red[4];
    if ((threadIdx.x & 63) == 0) red[threadIdx.x >> 6] = s;
    __syncthreads();
    if (threadIdx.x == 0) gp[bc] = (red[0] + red[1] + red[2] + red[3]) * inv;
}

// gpr2[bh][c] = relu( sum_k poolw_h[c][k] * gp[b][k] ), transpose-free
__global__ __launch_bounds__(TPB)
void poolconv2_k(const float* __restrict__ w0, const float* __restrict__ w1,
                 const float* __restrict__ gp, float* __restrict__ gpr2)
{
    const int bh = blockIdx.x;
    const int b = bh & 1;
    const float* w = (bh >> 1) ? w1 : w0;
    const int c = blockIdx.y * 16 + (threadIdx.x >> 4);
    const int kl = threadIdx.x & 15;
    const float* g = gp + (size_t)b * 2048;
    float s = 0.f;
    for (int k = kl; k < 2048; k += 16) s = fmaf(w[(size_t)c * 2048 + k], g[k], s);
#pragma unroll
    for (int o = 8; o; o >>= 1) s += __shfl_xor(s, o, 16);
    if (kl == 0) gpr2[bh * 256 + c] = fmaxf(s, 0.f);
}

// gpc2[bh][c] = sum_j aproj_h[c][1024+j] * gpr2[bh][j]
__global__ __launch_bounds__(TPB)
void gpc2_k(const float* __restrict__ a0, const float* __restrict__ a1,
            const float* __restrict__ gpr2, float* __restrict__ gpc2)
{
    const int bh = blockIdx.x;
    const float* w = (bh >> 1) ? a1 : a0;
    const int c = blockIdx.y * 16 + (threadIdx.x >> 4);
    const int kl = threadIdx.x & 15;
    const float* g = gpr2 + bh * 256;
    float s = 0.f;
    for (int j = kl; j < 256; j += 16) s = fmaf(w[(size_t)c * 1280 + 1024 + j], g[j], s);
#pragma unroll
    for (int o = 8; o; o >>= 1) s += __shfl_xor(s, o, 16);
    if (kl == 0) gpc2[bh * 256 + c] = s;
}

__global__ __launch_bounds__(TPB)
void biasfill2_k(const float* __restrict__ gpc2, float* __restrict__ yb)
{
    const int idx = blockIdx.x * TPB + threadIdx.x;
    if (idx >= 4 * 256 * 1089) return;
    const int c = (idx / 1089) & 255;
    const int s = idx / (256 * 1089);
    yb[idx] = gpc2[s * 256 + c];
}

// ---------- upsample 33->129 from pixel-major YBX2 (4 slots), writes CCX2 cols 48..303 ----------
__global__ __launch_bounds__(TPB)
void ups2_k(const f16* __restrict__ ybx, f16* __restrict__ ccx)
{
    const int idx = blockIdx.x * TPB + threadIdx.x;
    if (idx >= 4 * 16641 * 32) return;
    const int cg = idx & 31;
    const int p = (idx >> 5) % 16641;
    const int s = idx / (16641 * 32);
    const int oy = p / 129, ox = p % 129;
    const float sc = 33.0f / 129.0f;
    const float sx = (ox + 0.5f) * sc - 0.5f;
    const float sy = (oy + 0.5f) * sc - 0.5f;
    int ix0 = (int)floorf(sx), iy0 = (int)floorf(sy);
    const float fx = sx - ix0, fy = sy - iy0;
    int ix1 = min(32, max(0, ix0 + 1)); ix0 = min(32, max(0, ix0));
    int iy1 = min(32, max(0, iy0 + 1)); iy0 = min(32, max(0, iy0));
    const f16* base = ybx + (long)s * 1089 * 256 + cg * 8;
    const f16x8 v00 = *(const f16x8*)(base + ((long)iy0 * 33 + ix0) * 256);
    const f16x8 v01 = *(const f16x8*)(base + ((long)iy0 * 33 + ix1) * 256);
    const f16x8 v10 = *(const f16x8*)(base + ((long)iy1 * 33 + ix0) * 256);
    const f16x8 v11 = *(const f16x8*)(base + ((long)iy1 * 33 + ix1) * 256);
    f16x8 r;
#pragma unroll
    for (int e = 0; e < 8; ++e) {
        const float a0 = (float)v00[e] + ((float)v01[e] - (float)v00[e]) * fx;
        const float a1 = (float)v10[e] + ((float)v11[e] - (float)v10[e]) * fx;
        r[e] = (f16)(a0 + (a1 - a0) * fy);
    }
    *(f16x8*)(ccx + ((long)s * 16641 + p) * 320 + 48 + cg * 8) = r;
}

// ---------- cw2 1x1 conv, f16 input (already relu'd) ----------
template <int NC>
__global__ __launch_bounds__(TPB)
void conv1x1_small(const f16* __restrict__ in, const float* __restrict__ wT,
                   const float* __restrict__ bias, float* __restrict__ out, int HW)
{
    __shared__ float wsm[256 * NC];
    const int tid = threadIdx.x;
    for (int l = tid; l < 256 * NC; l += TPB) wsm[l] = wT[l];
    __syncthreads();
    const int b = blockIdx.y;
    const int p = blockIdx.x * TPB + tid;
    if (p >= HW) return;
    const f16* inB = in + (size_t)b * 256 * HW + p;
    float acc[NC];
#pragma unroll
    for (int c = 0; c < NC; ++c) acc[c] = 0.f;
    for (int k = 0; k < 256; ++k) {
        const float x = (float)inB[(size_t)k * HW];
#pragma unroll
        for (int c = 0; c < NC; ++c) acc[c] = fmaf(wsm[k * NC + c], x, acc[c]);
    }
    float* oB = out + (size_t)b * NC * HW + p;
#pragma unroll
    for (int c = 0; c < NC; ++c) oB[(size_t)c * HW] = acc[c] + bias[c];
}

// ---------- final: 129->513 bilinear + logits + NHWC features ----------
template <int NC>
__global__ __launch_bounds__(TPB)
void final_k(const float* __restrict__ x, float* __restrict__ logits,
             float* __restrict__ feats)
{
    const int idx = blockIdx.x * TPB + threadIdx.x;
    const long HW = 513L * 513L;
    if (idx >= 2 * 513 * 513) return;
    const int ox = idx % 513;
    int r = idx / 513;
    const int oy = r % 513;
    const int b = r / 513;
    const float sc = 129.0f / 513.0f;
    const float sx = (ox + 0.5f) * sc - 0.5f;
    const float sy = (oy + 0.5f) * sc - 0.5f;
    int ix0 = (int)floorf(sx), iy0 = (int)floorf(sy);
    const float fx = sx - ix0, fy = sy - iy0;
    int ix1 = min(128, max(0, ix0 + 1)); ix0 = min(128, max(0, ix0));
    int iy1 = min(128, max(0, iy0 + 1)); iy0 = min(128, max(0, iy0));
    const float* xb = x + (size_t)b * NC * 16641;
    const int i00 = iy0 * 129 + ix0, i01 = iy0 * 129 + ix1;
    const int i10 = iy1 * 129 + ix0, i11 = iy1 * 129 + ix1;
    float v[NC];
    float ss = 0.f;
#pragma unroll
    for (int c = 0; c < NC; ++c) {
        const float* s = xb + (size_t)c * 16641;
        const float a0 = s[i00] + (s[i01] - s[i00]) * fx;
        const float a1 = s[i10] + (s[i11] - s[i10]) * fx;
        const float vv = a0 + (a1 - a0) * fy;
        v[c] = vv;
        ss = fmaf(vv, vv, ss);
    }
    const long pix = (long)oy * 513 + ox;
#pragma unroll
    for (int c = 0; c < NC; ++c)
        logits[((size_t)b * NC + c) * HW + pix] = fmaf(6.f, v[c], -ss - 9.f);
    float* f = feats + ((size_t)b * HW + pix) * NC;
#pragma unroll
    for (int c = 0; c < NC; ++c) f[c] = v[c];
}

__global__ void centers_k(float* __restrict__ c0, float* __restrict__ c1)
{
    const int t = blockIdx.x * 64 + threadIdx.x;
    if (t < 256) c0[t] = (t / 16 == t % 16) ? 3.f : 0.f;
    const int u = t - 256;
    if (u >= 0 && u < 289) c1[u] = (u / 17 == u % 17) ? 3.f : 0.f;
}

// ---------------- host ----------------
extern "C" void kernel_launch(void* const* d_in, const int* in_sizes, int n_in,
                              void* d_out, int out_size, void* d_ws, size_t ws_size,
                              hipStream_t stream)
{
    const float* low_level = (const float*)d_in[0];
    const float* aspp_in   = (const float*)d_in[1];
    float* ws = (float*)d_ws;
    float* o  = (float*)d_out;

    // ---- ws layout (float offsets) ----
    f16*   GUARD   = (f16*)(ws + 0);                  //      4,096 fl zeros
    f16*   Apack2  = (f16*)(ws + 4096);               // 14,680,064 fl (2 heads); later C1O2 f16 alias
    f16*   C1O2    = (f16*)(ws + 4096);
    f16*   AprojP2 = (f16*)(ws + 14684160);           //    262,144 fl
    f16*   Cw1P2   = (f16*)(ws + 14946304);           //    737,280 fl
    f16*   LlP2    = (f16*)(ws + 15683584);           //     32,768 fl
    f16*   Xa      = (f16*)(ws + 15716352);           //  2,230,272 fl
    float* BRacc2  = ws + 17946624;                   //  4,460,544 fl
    f16*   BRX2    = (f16*)(ws + 22407168);           //  2,230,272 fl
    float* YB2     = ws + 24637440;                   //  1,115,136 fl
    f16*   YBX2    = (f16*)(ws + 25752576);           //    557,568 fl
    float* XB      = ws + 26310144;                   //    565,794 fl
    float* CW2T    = ws + 26875938;                   //      4,608 fl
    float* GP      = ws + 26880546;                   //      4,096 fl
    float* GPR2    = ws + 26884642;                   //      1,024 fl
    float* GPC2    = ws + 26885666;                   //      1,024 fl  (end 26,886,690 fl = 107.5 MB)

    // ---- d_out scratch (overwritten by final outputs afterwards) ----
    f16*   CCX2    = (f16*)(o + 0);                   // 10,650,240 fl (21.3M halves)
    f16*   Xll     = (f16*)(o + 10650240);            //  4,260,096 fl (8.52M halves)

    const long L0o = 0, L1o = 8421408, C0o = 17369154, C1oo = 17369410,
               F0o = 17369699, F1o = 25791107;

    hipMemsetAsync(GUARD, 0, 4096 * sizeof(float), stream);
    hipMemsetAsync(CCX2, 0, 21300480 * sizeof(f16), stream);  // pad cols stay 0

    // head-independent packs
    tc_k<0><<<dim3(35, 64, 2), TPB, 0, stream>>>(aspp_in, Xa, 2048, 1089, 2048, 0);
    {   // low_level -> Xll pixel-major f16 (2 slots, b only)
        tc_k<0><<<dim3(521, 8, 2), TPB, 0, stream>>>(low_level, Xll, 256, 16641, 256, 0);
    }
    gpool_k<<<4096, TPB, 0, stream>>>(aspp_in, GP, 1089, 1.0f / 1089.0f);

    // weight packs, both heads
    for (int h = 0; h < 2; ++h) {
        const float* w0    = (const float*)d_in[2 + h * 10 + 1];
        const float* w1    = (const float*)d_in[2 + h * 10 + 2];
        const float* w2    = (const float*)d_in[2 + h * 10 + 3];
        const float* w3    = (const float*)d_in[2 + h * 10 + 4];
        const float* aproj = (const float*)d_in[2 + h * 10 + 6];
        const float* cw1   = (const float*)d_in[2 + h * 10 + 7];
        const float* pw    = (const float*)d_in[2 + h * 10 + 0];
        f16* Ap = Apack2 + (long)h * 14680064;
        packw_k<<<dim3(32, 16), TPB, 0, stream>>>(w0, Ap,           256, 2048, 2048, 1, 256, 32);
        packw_k<<<dim3(32, 16), TPB, 0, stream>>>(w1, Ap + 524288,  256, 2048, 2048, 9, 256, 32);
        packw_k<<<dim3(32, 16), TPB, 0, stream>>>(w2, Ap + 5242880, 256, 2048, 2048, 9, 256, 32);
        packw_k<<<dim3(32, 16), TPB, 0, stream>>>(w3, Ap + 9961472, 256, 2048, 2048, 9, 256, 32);
        packw_k<<<dim3(16, 16), TPB, 0, stream>>>(aproj, AprojP2 + (long)h * 262144, 256, 1024, 1280, 1, 256, 16);
        packw_k<<<dim3(5, 16),  TPB, 0, stream>>>(cw1, Cw1P2 + (long)h * 737280, 256, 304, 304, 9, 256, 5);
        packw_k<<<dim3(4, 8),   TPB, 0, stream>>>(pw, LlP2 + (long)h * 32768, 48, 256, 256, 1, 128, 4);
    }

    // pooled branch (transpose-free), both heads -> bias prefill in YB2
    poolconv2_k<<<dim3(4, 16), TPB, 0, stream>>>(
        (const float*)d_in[2 + 5], (const float*)d_in[2 + 10 + 5], GP, GPR2);
    gpc2_k<<<dim3(4, 16), TPB, 0, stream>>>(
        (const float*)d_in[2 + 6], (const float*)d_in[2 + 10 + 6], GPR2, GPC2);
    biasfill2_k<<<4357, TPB, 0, stream>>>(GPC2, YB2);

    // fused ASPP, both heads: NZ=10 row-groups, atomic into zeroed BRacc2 (400 blocks)
    hipMemsetAsync(BRacc2, 0, 4460544 * sizeof(float), stream);
    mconv<2, 1, 0><<<400, TPB, 0, stream>>>(
        Xa, Apack2, GUARD, BRacc2, 2048, 256, 33, 33, 3, 1,
        64, 0, 0, 0L, 14680064L, 2230272L, 1115136L, 256, 0, 2, 4, 10);
    // relu + transpose -> BRX2 (4 slots)
    tc_k<1><<<dim3(35, 32, 4), TPB, 0, stream>>>(BRacc2, BRX2, 1024, 1089, 1024, 0);
    // aproj 1x1, split-K z=4, atomic into bias-prefilled YB2 (160 blocks)
    mconv<2, 2, 0><<<160, TPB, 0, stream>>>(
        BRX2, AprojP2, GUARD, YB2, 1024, 256, 33, 33, 1, 1,
        32, 1, 8, 2230272L, 262144L, 557568L, 278784L, 256, 0, 2, 4, 4);
    // relu + transpose YB2 -> YBX2 (4 slots)
    tc_k<1><<<dim3(35, 8, 4), TPB, 0, stream>>>(YB2, YBX2, 256, 1089, 256, 0);
    // low-level 1x1 (48ch, relu) -> CCX2 cols 0..47, both heads (264 blocks)
    mconv<3, 0, 1><<<264, TPB, 0, stream>>>(
        Xll, LlP2, GUARD, CCX2, 256, 48, 129, 129, 1, 1,
        8, 1, 0, 0L, 32768L, 10650240L, 5325120L, 128, 320, 1, 4, 1);
    // upsample 33->129 -> CCX2 cols 48..303 (4 slots)
    ups2_k<<<8321, TPB, 0, stream>>>(YBX2, CCX2);
    // cw1 3x3, full-K register accumulation, NO atomics, f16+relu store (528 blocks)
    mconv<1, 0, 1><<<528, TPB, 0, stream>>>(
        CCX2, Cw1P2, GUARD, C1O2, 320, 256, 129, 129, 3, 1,
        10, 9, 0, 10650240L, 737280L, 8520192L, 4260096L, 256, 0, 2, 4, 1);

    // cw2 + final per head (small)
    for (int h = 0; h < 2; ++h) {
        const float* cw2 = (const float*)d_in[2 + h * 10 + 8];
        const float* cb2 = (const float*)d_in[2 + h * 10 + 9];
        const f16* c1 = C1O2 + (long)h * 8520192;
        if (h == 0) {
            wtrans_f32<<<dim3(8, 1), TPB, 0, stream>>>(cw2, CW2T, 16, 256, 1);
            conv1x1_small<16><<<dim3(66, 2), TPB, 0, stream>>>(c1, CW2T, cb2, XB, 16641);
            final_k<16><<<2057, TPB, 0, stream>>>(XB, o + L0o, o + F0o);
        } else {
            wtrans_f32<<<dim3(8, 1), TPB, 0, stream>>>(cw2, CW2T, 17, 256, 1);
            conv1x1_small<17><<<dim3(66, 2), TPB, 0, stream>>>(c1, CW2T, cb2, XB, 16641);
            final_k<17><<<2057, TPB, 0, stream>>>(XB, o + L1o, o + F1o);
        }
    }
    centers_k<<<9, 64, 0, stream>>>(o + C0o, o + C1oo);
}

// Round 7
// 847.600 us; speedup vs baseline: 1.5687x; 1.0863x over previous
//
#include <hip/hip_runtime.h>

#define TPB 256

typedef _Float16 f16;
typedef __attribute__((ext_vector_type(8))) _Float16 f16x8;
typedef __attribute__((ext_vector_type(16))) float f32x16;

#define GLD_LDS(g, l) __builtin_amdgcn_global_load_lds( \
    (const __attribute__((address_space(1))) void*)(g), \
    (__attribute__((address_space(3))) void*)(l), 16, 0, 0)

// ---------- weight pack: w[Cout][CinSrc][T] f32 -> Wp[t][kb64][coP][64] f16 ----------
__global__ __launch_bounds__(TPB)
void packw_k(const float* __restrict__ w, f16* __restrict__ dst,
             int Cout, int CinUse, int CinSrc, int T, int coP, int KB)
{
    __shared__ float tile[16 * 577];
    const int RL = 64 * T;
    const int kb = blockIdx.x;
    const int coT = blockIdx.y;
    const int tid = threadIdx.x;
    const int n = 16 * RL;
    for (int idx = tid; idx < n; idx += TPB) {
        const int row = idx / RL;
        const int j = idx - row * RL;
        const int co = coT * 16 + row;
        const int k = kb * 64 + j / T;
        float v = 0.f;
        if (co < Cout && k < CinUse)
            v = w[((long)co * CinSrc + kb * 64) * T + j];
        tile[row * 577 + j] = v;
    }
    __syncthreads();
    const int nst = 128 * T;
    for (int idx = tid; idx < nst; idx += TPB) {
        const int g = idx & 7;
        const int t = (idx >> 3) % T;
        const int co = idx / (8 * T);
        f16x8 hv;
#pragma unroll
        for (int e = 0; e < 8; ++e)
            hv[e] = (f16)tile[co * 577 + (g * 8 + e) * T + t];
        *(f16x8*)&dst[(((long)t * KB + kb) * coP + coT * 16 + co) * 64 + g * 8] = hv;
    }
}

// ---------- transpose-cvt: src[S][C][HW] f32 -> dst[S][HW][ldk] f16 ----------
template <int RELU>
__global__ __launch_bounds__(TPB)
void tc_k(const float* __restrict__ src, f16* __restrict__ dst,
          int C, int HW, int ldk, int colOff)
{
    __shared__ float t32[32 * 33];
    const int pT = blockIdx.x, cT = blockIdx.y, bb = blockIdx.z;
    const int tid = threadIdx.x;
#pragma unroll
    for (int pass = 0; pass < 4; ++pass) {
        const int ch = tid / 32 + pass * 8;
        const int px = tid % 32;
        const int c = cT * 32 + ch, p = pT * 32 + px;
        float v = 0.f;
        if (c < C && p < HW) v = src[((long)bb * C + c) * HW + p];
        if (RELU) v = fmaxf(v, 0.f);
        t32[ch * 33 + px] = v;
    }
    __syncthreads();
#pragma unroll
    for (int pass = 0; pass < 4; ++pass) {
        const int px = tid / 32 + pass * 8;
        const int ch = tid % 32;
        const int p = pT * 32 + px, c = cT * 32 + ch;
        if (p < HW && c < C)
            dst[((long)bb * HW + p) * ldk + colOff + c] = (f16)t32[ch * 33 + px];
    }
}

// ---------- MFMA implicit-GEMM conv: m97-style single-buffer, BK=64, 128x128 tile ----------
// X: [b][NP][Cinp] f16 pixel-major (+ strides). Wp: [t][kb64][coP][64] f16 (+ head stride).
// 4 waves 2x2, wave tile 64x64, 16 MFMA(32x32x16) per K-step, 32KB LDS, 4 blocks/CU.
// OUTMODE: 0=f32 ch-major, 1=f16 ch-major, 2=atomicAdd f32 ch-major, 3=f16 pixel-major.
// ZMAP: 0 = plain (all taps, full K), 1 = ASPP (z -> branch/row-group band).
template <int OUTMODE, int ZMAP, int RELUOUT, int BIAS>
__global__ __launch_bounds__(TPB, 4)
void mconv(const f16* __restrict__ X, const f16* __restrict__ Wp,
           const f16* __restrict__ guard, void* __restrict__ out_,
           const float* __restrict__ gpc,
           int Cinp, int Cout, int H, int W, int kss_, int dl_,
           int kbPerTap, int tapCnt_,
           long xHstr, long wHstr, long oHstr, long outBStride,
           int coP, int ldOut, int NM, int NBH, int NZ)
{
    __shared__ char SH[32768];
    const int tid = threadIdx.x;

    // XCD chunk-swizzle (m204 bijective)
    int wg;
    {
        const int orig = blockIdx.x, nwg = gridDim.x;
        const int q = nwg >> 3, r = nwg & 7;
        const int xcd = orig & 7, off = orig >> 3;
        wg = (xcd < r ? xcd * (q + 1) : r * (q + 1) + (xcd - r) * q) + off;
    }
    const int mt = wg % NM; wg /= NM;
    const int bh = wg % NBH; wg /= NBH;
    const int z  = wg % NZ;
    const int nt = wg / NZ;
    const int b = bh & 1, hd = bh >> 1;
    const int co0 = mt * 128;
    const int NP = H * W;
    const long xBstr = (long)NP * Cinp;

    int kss = kss_, dl = dl_, tapStart = 0, tapCnt = tapCnt_;
    long woff = (long)hd * wHstr, ooff = (long)hd * oHstr;
    int p0 = nt * 128, pMax = NP;
    if (ZMAP == 1) {
        int br, grp;
        if (z == 0) { br = 0; grp = 1; kss = 1; dl = 1; tapStart = 0; tapCnt = 1; }
        else { br = 1 + (z - 1) / 3; grp = (z - 1) % 3;
               kss = 3; dl = (br == 1) ? 6 : (br == 2 ? 12 : 18);
               tapStart = grp * 3; tapCnt = 3; }
        woff += (br == 0) ? 0L : (br == 1 ? 524288L : (br == 2 ? 5242880L : 9961472L));
        ooff += (long)br * 278784L;
        const int dy0 = (kss == 1) ? 0 : (grp - 1) * dl;
        const int yLo = max(0, -dy0), yHi = min(H, H - dy0);
        p0 = yLo * W + nt * 128;
        pMax = yHi * W;
        if (p0 >= pMax) return;
    }
    const int half = kss >> 1;
    const int y0t = p0 / W, y1t = min(p0 + 127, pMax - 1) / W;

    // valid tap list (block-uniform skip)
    int taps[9]; int nval = 0;
    for (int t = 0; t < tapCnt; ++t) {
        const int tp = tapStart + t;
        const int ky = tp / kss;
        const int dy = (ky - half) * dl;
        if (ZMAP == 1 || (y1t + dy >= 0 && y0t + dy < H)) taps[nval++] = tp;
    }
    if (nval == 0) return;  // only possible in atomic mode

    // ---- staging geometry: thread t covers (row = q*32 + t/8, slot = t&7), 4 rounds each for A,B ----
    const int srow = tid >> 3;
    const int sslot = tid & 7;
    int aofs[4];
#pragma unroll
    for (int q = 0; q < 4; ++q) {
        const int row = q * 32 + srow;
        aofs[q] = row * 64 + ((sslot ^ (row & 7)) << 3);   // f16 units, pre-swizzled source
    }
    const long coStr = (long)coP * 64;

    // ---- compute roles ----
    const int lane = tid & 63, wid = tid >> 6;
    const int wm = wid >> 1, wn = wid & 1;
    const int r32 = lane & 31, hh = lane >> 5;
    const int arow0 = wm * 64 + r32, arow1 = arow0 + 32;
    const int brow0 = wn * 64 + r32, brow1 = brow0 + 32;
    const int abase0 = arow0 * 128, abase1 = arow1 * 128;
    const int bbase0 = 16384 + brow0 * 128, bbase1 = 16384 + brow1 * 128;
    const int ax0 = (arow0 & 7), ax1 = (arow1 & 7);
    const int bx0 = (brow0 & 7), bx1 = (brow1 & 7);

    f32x16 acc[2][2];
#pragma unroll
    for (int i = 0; i < 2; ++i)
#pragma unroll
        for (int j = 0; j < 2; ++j) acc[i][j] = (f32x16)(0.f);

    const f16* Pr[4];
    for (int ti = 0; ti < nval; ++ti) {
        const int tp = taps[ti];
        const int ky = tp / kss, kx = tp - ky * kss;
        const int dy = (ky - half) * dl, dx = (kx - half) * dl;
#pragma unroll
        for (int q = 0; q < 4; ++q) {
            const int row = q * 32 + srow;
            const int p = p0 + row;
            bool v = p < pMax;
            const int py = v ? p / W : 0;
            const int px = v ? p - py * W : 0;
            const int sy = py + dy, sx = px + dx;
            v = v && ((unsigned)sy < (unsigned)H) && ((unsigned)sx < (unsigned)W);
            const int swz = (sslot ^ (row & 7)) << 3;
            Pr[q] = v ? (X + (long)b * xBstr + (long)hd * xHstr
                           + ((long)sy * W + sx) * (long)Cinp + swz)
                      : (guard + swz);
        }
        const f16* Wt = Wp + woff + ((long)tp * kbPerTap * coP + (long)co0) * 64;
        for (int kb = 0; kb < kbPerTap; ++kb) {
            __syncthreads();
            const f16* wsrc = Wt + (long)kb * coStr;
            const long kcol = (long)kb << 6;
            GLD_LDS(wsrc + aofs[0], SH + (tid << 4));
            GLD_LDS(wsrc + aofs[1], SH + 4096 + (tid << 4));
            GLD_LDS(wsrc + aofs[2], SH + 8192 + (tid << 4));
            GLD_LDS(wsrc + aofs[3], SH + 12288 + (tid << 4));
            GLD_LDS(Pr[0] + kcol, SH + 16384 + (tid << 4));
            GLD_LDS(Pr[1] + kcol, SH + 20480 + (tid << 4));
            GLD_LDS(Pr[2] + kcol, SH + 24576 + (tid << 4));
            GLD_LDS(Pr[3] + kcol, SH + 28672 + (tid << 4));
            __syncthreads();
            __builtin_amdgcn_s_setprio(1);
#pragma unroll
            for (int kh = 0; kh < 4; ++kh) {
                const int g = kh * 2 + hh;
                const f16x8 a0 = *(const f16x8*)(SH + abase0 + ((g ^ ax0) << 4));
                const f16x8 a1 = *(const f16x8*)(SH + abase1 + ((g ^ ax1) << 4));
                const f16x8 b0 = *(const f16x8*)(SH + bbase0 + ((g ^ bx0) << 4));
                const f16x8 b1 = *(const f16x8*)(SH + bbase1 + ((g ^ bx1) << 4));
                acc[0][0] = __builtin_amdgcn_mfma_f32_32x32x16_f16(a0, b0, acc[0][0], 0, 0, 0);
                acc[0][1] = __builtin_amdgcn_mfma_f32_32x32x16_f16(a0, b1, acc[0][1], 0, 0, 0);
                acc[1][0] = __builtin_amdgcn_mfma_f32_32x32x16_f16(a1, b0, acc[1][0], 0, 0, 0);
                acc[1][1] = __builtin_amdgcn_mfma_f32_32x32x16_f16(a1, b1, acc[1][1], 0, 0, 0);
            }
            __builtin_amdgcn_s_setprio(0);
        }
    }

    // ---- epilogue ----
    const long outB = (long)b * outBStride + ooff;
    const float* gpcp = BIAS ? (gpc + (long)(b + 2 * hd) * 256) : nullptr;
#pragma unroll
    for (int mi = 0; mi < 2; ++mi)
#pragma unroll
    for (int ni = 0; ni < 2; ++ni)
#pragma unroll
    for (int j = 0; j < 16; ++j) {
        const int m = wm * 64 + mi * 32 + 4 * hh + (j & 3) + 8 * (j >> 2);
        const int n = wn * 64 + ni * 32 + r32;
        const int co = co0 + m;
        const int p = p0 + n;
        if (co < Cout && p < pMax) {
            float v = acc[mi][ni][j];
            if (BIAS) v += gpcp[co];
            if (RELUOUT) v = fmaxf(v, 0.f);
            if (OUTMODE == 0)      ((float*)out_)[outB + (long)co * NP + p] = v;
            else if (OUTMODE == 1) ((f16*)out_)[outB + (long)co * NP + p] = (f16)v;
            else if (OUTMODE == 3) ((f16*)out_)[outB + (long)p * ldOut + co] = (f16)v;
            else atomicAdd(&((float*)out_)[outB + (long)co * NP + p], v);
        }
    }
}

// ---------- small helpers ----------
__global__ __launch_bounds__(TPB)
void wtrans_f32(const float* __restrict__ w, float* __restrict__ wT,
                int Cout, int Cin, int T)
{
    __shared__ float tile[32 * (32 * 9 + 1)];
    const int rowlen = 32 * T + 1;
    const int co0 = blockIdx.y * 32;
    const int ci0 = blockIdx.x * 32;
    const int n = 32 * 32 * T;
    const int tid = threadIdx.x;
    for (int l = tid; l < n; l += TPB) {
        int co = l / (32 * T);
        int rem = l - co * (32 * T);
        int ci = rem / T;
        float v = 0.f;
        if (co0 + co < Cout && ci0 + ci < Cin)
            v = w[(size_t)(co0 + co) * Cin * T + (size_t)ci0 * T + rem];
        tile[co * rowlen + rem] = v;
    }
    __syncthreads();
    for (int l = tid; l < n; l += TPB) {
        int co = l & 31;
        int ci = (l >> 5) & 31;
        int t = l >> 10;
        if (co0 + co < Cout && ci0 + ci < Cin)
            wT[((size_t)t * Cin + (ci0 + ci)) * Cout + (co0 + co)] = tile[co * rowlen + ci * T + t];
    }
}

__global__ __launch_bounds__(TPB)
void gpool_k(const float* __restrict__ in, float* __restrict__ gp, int HW, float inv)
{
    const int bc = blockIdx.x;
    const float* p = in + (size_t)bc * HW;
    float s = 0.f;
    for (int i = threadIdx.x; i < HW; i += TPB) s += p[i];
#pragma unroll
    for (int off = 32; off > 0; off >>= 1) s += __shfl_down(s, off, 64);
    __shared__ float red[4];
    if ((threadIdx.x & 63) == 0) red[threadIdx.x >> 6] = s;
    __syncthreads();
    if (threadIdx.x == 0) gp[bc] = (red[0] + red[1] + red[2] + red[3]) * inv;
}

__global__ __launch_bounds__(TPB)
void poolconv2_k(const float* __restrict__ w0, const float* __restrict__ w1,
                 const float* __restrict__ gp, float* __restrict__ gpr2)
{
    const int bh = blockIdx.x;
    const int b = bh & 1;
    const float* w = (bh >> 1) ? w1 : w0;
    const int c = blockIdx.y * 16 + (threadIdx.x >> 4);
    const int kl = threadIdx.x & 15;
    const float* g = gp + (size_t)b * 2048;
    float s = 0.f;
    for (int k = kl; k < 2048; k += 16) s = fmaf(w[(size_t)c * 2048 + k], g[k], s);
#pragma unroll
    for (int o = 8; o; o >>= 1) s += __shfl_xor(s, o, 16);
    if (kl == 0) gpr2[bh * 256 + c] = fmaxf(s, 0.f);
}

__global__ __launch_bounds__(TPB)
void gpc2_k(const float* __restrict__ a0, const float* __restrict__ a1,
            const float* __restrict__ gpr2, float* __restrict__ gpc2)
{
    const int bh = blockIdx.x;
    const float* w = (bh >> 1) ? a1 : a0;
    const int c = blockIdx.y * 16 + (threadIdx.x >> 4);
    const int kl = threadIdx.x & 15;
    const float* g = gpr2 + bh * 256;
    float s = 0.f;
    for (int j = kl; j < 256; j += 16) s = fmaf(w[(size_t)c * 1280 + 1024 + j], g[j], s);
#pragma unroll
    for (int o = 8; o; o >>= 1) s += __shfl_xor(s, o, 16);
    if (kl == 0) gpc2[bh * 256 + c] = s;
}

// ---------- upsample 33->129 from pixel-major YBX2 (4 slots), writes CCX2 cols 48..303 ----------
__global__ __launch_bounds__(TPB)
void ups2_k(const f16* __restrict__ ybx, f16* __restrict__ ccx)
{
    const int idx = blockIdx.x * TPB + threadIdx.x;
    if (idx >= 4 * 16641 * 32) return;
    const int cg = idx & 31;
    const int p = (idx >> 5) % 16641;
    const int s = idx / (16641 * 32);
    const int oy = p / 129, ox = p % 129;
    const float sc = 33.0f / 129.0f;
    const float sx = (ox + 0.5f) * sc - 0.5f;
    const float sy = (oy + 0.5f) * sc - 0.5f;
    int ix0 = (int)floorf(sx), iy0 = (int)floorf(sy);
    const float fx = sx - ix0, fy = sy - iy0;
    int ix1 = min(32, max(0, ix0 + 1)); ix0 = min(32, max(0, ix0));
    int iy1 = min(32, max(0, iy0 + 1)); iy0 = min(32, max(0, iy0));
    const f16* base = ybx + (long)s * 1089 * 256 + cg * 8;
    const f16x8 v00 = *(const f16x8*)(base + ((long)iy0 * 33 + ix0) * 256);
    const f16x8 v01 = *(const f16x8*)(base + ((long)iy0 * 33 + ix1) * 256);
    const f16x8 v10 = *(const f16x8*)(base + ((long)iy1 * 33 + ix0) * 256);
    const f16x8 v11 = *(const f16x8*)(base + ((long)iy1 * 33 + ix1) * 256);
    f16x8 r;
#pragma unroll
    for (int e = 0; e < 8; ++e) {
        const float a0 = (float)v00[e] + ((float)v01[e] - (float)v00[e]) * fx;
        const float a1 = (float)v10[e] + ((float)v11[e] - (float)v10[e]) * fx;
        r[e] = (f16)(a0 + (a1 - a0) * fy);
    }
    *(f16x8*)(ccx + ((long)s * 16641 + p) * 320 + 48 + cg * 8) = r;
}

// ---------- cw2 1x1 conv, f16 input (already relu'd) ----------
template <int NC>
__global__ __launch_bounds__(TPB)
void conv1x1_small(const f16* __restrict__ in, const float* __restrict__ wT,
                   const float* __restrict__ bias, float* __restrict__ out, int HW)
{
    __shared__ float wsm[256 * NC];
    const int tid = threadIdx.x;
    for (int l = tid; l < 256 * NC; l += TPB) wsm[l] = wT[l];
    __syncthreads();
    const int b = blockIdx.y;
    const int p = blockIdx.x * TPB + tid;
    if (p >= HW) return;
    const f16* inB = in + (size_t)b * 256 * HW + p;
    float acc[NC];
#pragma unroll
    for (int c = 0; c < NC; ++c) acc[c] = 0.f;
    for (int k = 0; k < 256; ++k) {
        const float x = (float)inB[(size_t)k * HW];
#pragma unroll
        for (int c = 0; c < NC; ++c) acc[c] = fmaf(wsm[k * NC + c], x, acc[c]);
    }
    float* oB = out + (size_t)b * NC * HW + p;
#pragma unroll
    for (int c = 0; c < NC; ++c) oB[(size_t)c * HW] = acc[c] + bias[c];
}

// ---------- final: 129->513 bilinear + logits + NHWC features ----------
template <int NC>
__global__ __launch_bounds__(TPB)
void final_k(const float* __restrict__ x, float* __restrict__ logits,
             float* __restrict__ feats)
{
    const int idx = blockIdx.x * TPB + threadIdx.x;
    const long HW = 513L * 513L;
    if (idx >= 2 * 513 * 513) return;
    const int ox = idx % 513;
    int r = idx / 513;
    const int oy = r % 513;
    const int b = r / 513;
    const float sc = 129.0f / 513.0f;
    const float sx = (ox + 0.5f) * sc - 0.5f;
    const float sy = (oy + 0.5f) * sc - 0.5f;
    int ix0 = (int)floorf(sx), iy0 = (int)floorf(sy);
    const float fx = sx - ix0, fy = sy - iy0;
    int ix1 = min(128, max(0, ix0 + 1)); ix0 = min(128, max(0, ix0));
    int iy1 = min(128, max(0, iy0 + 1)); iy0 = min(128, max(0, iy0));
    const float* xb = x + (size_t)b * NC * 16641;
    const int i00 = iy0 * 129 + ix0, i01 = iy0 * 129 + ix1;
    const int i10 = iy1 * 129 + ix0, i11 = iy1 * 129 + ix1;
    float v[NC];
    float ss = 0.f;
#pragma unroll
    for (int c = 0; c < NC; ++c) {
        const float* s = xb + (size_t)c * 16641;
        const float a0 = s[i00] + (s[i01] - s[i00]) * fx;
        const float a1 = s[i10] + (s[i11] - s[i10]) * fx;
        const float vv = a0 + (a1 - a0) * fy;
        v[c] = vv;
        ss = fmaf(vv, vv, ss);
    }
    const long pix = (long)oy * 513 + ox;
#pragma unroll
    for (int c = 0; c < NC; ++c)
        logits[((size_t)b * NC + c) * HW + pix] = fmaf(6.f, v[c], -ss - 9.f);
    float* f = feats + ((size_t)b * HW + pix) * NC;
#pragma unroll
    for (int c = 0; c < NC; ++c) f[c] = v[c];
}

__global__ void centers_k(float* __restrict__ c0, float* __restrict__ c1)
{
    const int t = blockIdx.x * 64 + threadIdx.x;
    if (t < 256) c0[t] = (t / 16 == t % 16) ? 3.f : 0.f;
    const int u = t - 256;
    if (u >= 0 && u < 289) c1[u] = (u / 17 == u % 17) ? 3.f : 0.f;
}

// ---------------- host ----------------
extern "C" void kernel_launch(void* const* d_in, const int* in_sizes, int n_in,
                              void* d_out, int out_size, void* d_ws, size_t ws_size,
                              hipStream_t stream)
{
    const float* low_level = (const float*)d_in[0];
    const float* aspp_in   = (const float*)d_in[1];
    float* ws = (float*)d_ws;
    float* o  = (float*)d_out;

    // ---- ws layout (float offsets) ----
    f16*   GUARD   = (f16*)(ws + 0);                  //      4,096 fl zeros
    f16*   Apack2  = (f16*)(ws + 4096);               // 14,680,064 fl (2 heads); later C1O2 alias
    f16*   C1O2    = (f16*)(ws + 4096);
    f16*   AprojP2 = (f16*)(ws + 14684160);           //    262,144 fl
    f16*   Cw1P2   = (f16*)(ws + 14946304);           //    737,280 fl
    f16*   LlP2    = (f16*)(ws + 15683584);           //     32,768 fl
    f16*   Xa      = (f16*)(ws + 15716352);           //  2,230,272 fl
    float* BRacc2  = ws + 17946624;                   //  4,460,544 fl
    f16*   BRX2    = (f16*)(ws + 22407168);           //  2,230,272 fl
    f16*   YBX2    = (f16*)(ws + 24637440);           //    557,568 fl
    float* XB      = ws + 25195008;                   //    565,794 fl
    float* CW2T    = ws + 25760802;                   //      4,608 fl
    float* GP      = ws + 25765410;                   //      4,096 fl
    float* GPR2    = ws + 25769506;                   //      1,024 fl
    float* GPC2    = ws + 25770530;                   //      1,024 fl

    // ---- d_out scratch (overwritten by final outputs afterwards) ----
    f16*   CCX2    = (f16*)(o + 0);                   // 21.3M halves
    f16*   Xll     = (f16*)(o + 10650240);            //  8.52M halves

    const long L0o = 0, L1o = 8421408, C0o = 17369154, C1oo = 17369410,
               F0o = 17369699, F1o = 25791107;

    hipMemsetAsync(GUARD, 0, 4096 * sizeof(float), stream);
    hipMemsetAsync(CCX2, 0, 21300480 * sizeof(f16), stream);  // pad cols stay 0

    // head-independent packs
    tc_k<0><<<dim3(35, 64, 2), TPB, 0, stream>>>(aspp_in, Xa, 2048, 1089, 2048, 0);
    tc_k<0><<<dim3(521, 8, 2), TPB, 0, stream>>>(low_level, Xll, 256, 16641, 256, 0);
    gpool_k<<<4096, TPB, 0, stream>>>(aspp_in, GP, 1089, 1.0f / 1089.0f);

    // weight packs, both heads
    for (int h = 0; h < 2; ++h) {
        const float* pw    = (const float*)d_in[2 + h * 10 + 0];
        const float* w0    = (const float*)d_in[2 + h * 10 + 1];
        const float* w1    = (const float*)d_in[2 + h * 10 + 2];
        const float* w2    = (const float*)d_in[2 + h * 10 + 3];
        const float* w3    = (const float*)d_in[2 + h * 10 + 4];
        const float* aproj = (const float*)d_in[2 + h * 10 + 6];
        const float* cw1   = (const float*)d_in[2 + h * 10 + 7];
        f16* Ap = Apack2 + (long)h * 14680064;
        packw_k<<<dim3(32, 16), TPB, 0, stream>>>(w0, Ap,           256, 2048, 2048, 1, 256, 32);
        packw_k<<<dim3(32, 16), TPB, 0, stream>>>(w1, Ap + 524288,  256, 2048, 2048, 9, 256, 32);
        packw_k<<<dim3(32, 16), TPB, 0, stream>>>(w2, Ap + 5242880, 256, 2048, 2048, 9, 256, 32);
        packw_k<<<dim3(32, 16), TPB, 0, stream>>>(w3, Ap + 9961472, 256, 2048, 2048, 9, 256, 32);
        packw_k<<<dim3(16, 16), TPB, 0, stream>>>(aproj, AprojP2 + (long)h * 262144, 256, 1024, 1280, 1, 256, 16);
        packw_k<<<dim3(5, 16),  TPB, 0, stream>>>(cw1, Cw1P2 + (long)h * 737280, 256, 304, 304, 9, 256, 5);
        packw_k<<<dim3(4, 8),   TPB, 0, stream>>>(pw, LlP2 + (long)h * 32768, 48, 256, 256, 1, 128, 4);
    }

    // pooled branch -> GPC2 (bias applied in aproj epilogue)
    poolconv2_k<<<dim3(4, 16), TPB, 0, stream>>>(
        (const float*)d_in[2 + 5], (const float*)d_in[2 + 10 + 5], GP, GPR2);
    gpc2_k<<<dim3(4, 16), TPB, 0, stream>>>(
        (const float*)d_in[2 + 6], (const float*)d_in[2 + 10 + 6], GPR2, GPC2);

    // fused ASPP, both heads: NT9 x NM2 x NBH4 x NZ10 = 720 blocks, atomic -> BRacc2
    hipMemsetAsync(BRacc2, 0, 4460544 * sizeof(float), stream);
    mconv<2, 1, 0, 0><<<720, TPB, 0, stream>>>(
        Xa, Apack2, GUARD, BRacc2, nullptr, 2048, 256, 33, 33, 3, 1,
        32, 0, 0L, 14680064L, 2230272L, 1115136L, 256, 0, 2, 4, 10);
    // relu + transpose -> BRX2 (4 slots)
    tc_k<1><<<dim3(35, 32, 4), TPB, 0, stream>>>(BRacc2, BRX2, 1024, 1089, 1024, 0);
    // aproj 1x1, FULL-K per block, bias+relu, f16 pixel-major -> YBX2 (72 blocks)
    mconv<3, 0, 1, 1><<<72, TPB, 0, stream>>>(
        BRX2, AprojP2, GUARD, YBX2, GPC2, 1024, 256, 33, 33, 1, 1,
        16, 1, 2230272L, 262144L, 557568L, 278784L, 256, 256, 2, 4, 1);
    // low-level 1x1 (48ch, relu) -> CCX2 cols 0..47 (524 blocks)
    mconv<3, 0, 1, 0><<<524, TPB, 0, stream>>>(
        Xll, LlP2, GUARD, CCX2, nullptr, 256, 48, 129, 129, 1, 1,
        4, 1, 0L, 32768L, 10650240L, 5325120L, 128, 320, 1, 4, 1);
    // upsample 33->129 -> CCX2 cols 48..303 (4 slots)
    ups2_k<<<8321, TPB, 0, stream>>>(YBX2, CCX2);
    // cw1 3x3, full-K reg accumulation, f16+relu store (1048 blocks)
    mconv<1, 0, 1, 0><<<1048, TPB, 0, stream>>>(
        CCX2, Cw1P2, GUARD, C1O2, nullptr, 320, 256, 129, 129, 3, 1,
        5, 9, 10650240L, 737280L, 8520192L, 4260096L, 256, 0, 2, 4, 1);

    // cw2 + final per head
    for (int h = 0; h < 2; ++h) {
        const float* cw2 = (const float*)d_in[2 + h * 10 + 8];
        const float* cb2 = (const float*)d_in[2 + h * 10 + 9];
        const f16* c1 = C1O2 + (long)h * 8520192;
        if (h == 0) {
            wtrans_f32<<<dim3(8, 1), TPB, 0, stream>>>(cw2, CW2T, 16, 256, 1);
            conv1x1_small<16><<<dim3(66, 2), TPB, 0, stream>>>(c1, CW2T, cb2, XB, 16641);
            final_k<16><<<2057, TPB, 0, stream>>>(XB, o + L0o, o + F0o);
        } else {
            wtrans_f32<<<dim3(8, 1), TPB, 0, stream>>>(cw2, CW2T, 17, 256, 1);
            conv1x1_small<17><<<dim3(66, 2), TPB, 0, stream>>>(c1, CW2T, cb2, XB, 16641);
            final_k<17><<<2057, TPB, 0, stream>>>(XB, o + L1o, o + F1o);
        }
    }
    centers_k<<<9, 64, 0, stream>>>(o + C0o, o + C1oo);
}